// Round 1
// baseline (446.053 us; speedup 1.0000x reference)
//
#include <hip/hip_runtime.h>
#include <math.h>

#define TOKENS 16384
#define DIM 2048
#define NE 64
#define BT 64            // tokens per block
#define KC 64            // k-chunk
#define NCHUNK (DIM / KC)
#define XS 68            // padded LDS row stride for x tile (16B-aligned, breaks bank aliasing)

// ---------------- Kernel A: transpose W [64][2048] -> wt [2048][64] ----------------
__global__ __launch_bounds__(256) void wtrans_kernel(const float* __restrict__ W,
                                                     float* __restrict__ wt) {
    __shared__ float tile[64 * 129];
    const int k0 = blockIdx.x * 128;
    const int tid = threadIdx.x;
    const int half = tid >> 7;     // 0..1
    const int c = tid & 127;       // 0..127
    for (int r = 0; r < 32; ++r) {
        int e = r * 2 + half;
        tile[e * 129 + c] = W[e * DIM + k0 + c];   // coalesced read along W row
    }
    __syncthreads();
    const int ec = tid & 63;
    const int kq = tid >> 6;       // 0..3
    for (int p = 0; p < 32; ++p) {
        int kr = p * 4 + kq;
        wt[(k0 + kr) * 64 + ec] = tile[ec * 129 + kr];  // coalesced write along wt row
    }
}

// ---------------- Kernel B: fused logits GEMM + top-2 + softmax ----------------
__global__ __launch_bounds__(256) void router_kernel(const float* __restrict__ x,
                                                     const float* __restrict__ wt,
                                                     const float* __restrict__ b,
                                                     float* __restrict__ out) {
    __shared__ float x_s[BT * XS];     // [t][k], stride 68
    __shared__ float w_s[KC * NE];     // [k][e], stride 64; reused as logits tile in phase 2

    const int tid = threadIdx.x;
    const int t0 = blockIdx.x * BT;
    const int e0 = (tid & 15) * 4;     // expert group (4 experts)
    const int tl = (tid >> 4) * 4;     // token group (4 tokens)

    float acc[4][4] = {};
    float4 xr[4], wr[4];

    const float4* wt4 = (const float4*)wt;

    auto load_chunk = [&](int kc) {
        #pragma unroll
        for (int p = 0; p < 4; ++p) {
            int idx = p * 256 + tid;
            int tr = idx >> 4;         // 0..63
            int cc = idx & 15;         // 0..15 (float4 within 64-float row)
            xr[p] = *(const float4*)&x[(size_t)(t0 + tr) * DIM + kc * KC + cc * 4];
            wr[p] = wt4[kc * (KC * NE / 4) + idx];   // fully contiguous
        }
    };
    auto store_chunk = [&]() {
        #pragma unroll
        for (int p = 0; p < 4; ++p) {
            int idx = p * 256 + tid;
            int tr = idx >> 4;
            int cc = idx & 15;
            *(float4*)&x_s[tr * XS + cc * 4] = xr[p];
            *(float4*)&w_s[idx * 4] = wr[p];
        }
    };

    load_chunk(0);
    store_chunk();
    __syncthreads();

    for (int kc = 0; kc < NCHUNK; ++kc) {
        if (kc + 1 < NCHUNK) load_chunk(kc + 1);   // global -> regs, hidden behind compute
        #pragma unroll
        for (int kk = 0; kk < KC; kk += 4) {
            float4 xa[4], wa[4];
            #pragma unroll
            for (int i = 0; i < 4; ++i) xa[i] = *(const float4*)&x_s[(tl + i) * XS + kk];
            #pragma unroll
            for (int j = 0; j < 4; ++j) wa[j] = *(const float4*)&w_s[(kk + j) * NE + e0];
            #pragma unroll
            for (int i = 0; i < 4; ++i) {
                const float* xi = (const float*)&xa[i];
                #pragma unroll
                for (int j = 0; j < 4; ++j) {
                    const float* wj = (const float*)&wa[j];
                    acc[i][0] += xi[j] * wj[0];
                    acc[i][1] += xi[j] * wj[1];
                    acc[i][2] += xi[j] * wj[2];
                    acc[i][3] += xi[j] * wj[3];
                }
            }
        }
        __syncthreads();
        if (kc + 1 < NCHUNK) {
            store_chunk();
            __syncthreads();
        }
    }

    // ---- epilogue: bias, logits out, stage tile for top-k ----
    float* logits_out = out + (size_t)TOKENS * 2 * 2;   // after probs + indices
    #pragma unroll
    for (int i = 0; i < 4; ++i) {
        float4 v;
        v.x = acc[i][0] + b[e0 + 0];
        v.y = acc[i][1] + b[e0 + 1];
        v.z = acc[i][2] + b[e0 + 2];
        v.w = acc[i][3] + b[e0 + 3];
        *(float4*)&logits_out[(size_t)(t0 + tl + i) * NE + e0] = v;
        *(float4*)&w_s[(tl + i) * NE + e0] = v;
    }
    __syncthreads();

    // ---- phase 2: one wave per token, top-2 + softmax ----
    const int lane = tid & 63;
    const int wv = tid >> 6;
    for (int tt = 0; tt < 16; ++tt) {
        int t = wv * 16 + tt;
        float v = w_s[t * NE + lane];

        float v1 = v; int i1 = lane;
        #pragma unroll
        for (int off = 32; off >= 1; off >>= 1) {
            float ov = __shfl_xor(v1, off, 64);
            int   oi = __shfl_xor(i1, off, 64);
            if (ov > v1 || (ov == v1 && oi < i1)) { v1 = ov; i1 = oi; }
        }
        float vm = (lane == i1) ? -INFINITY : v;
        float v2 = vm; int i2 = lane;
        #pragma unroll
        for (int off = 32; off >= 1; off >>= 1) {
            float ov = __shfl_xor(v2, off, 64);
            int   oi = __shfl_xor(i2, off, 64);
            if (ov > v2 || (ov == v2 && oi < i2)) { v2 = ov; i2 = oi; }
        }

        if (lane == 0) {
            int tg = t0 + t;
            float e1 = expf(v2 - v1);          // v1 >= v2, stable
            float s = 1.0f + e1;
            out[(size_t)tg * 2 + 0] = 1.0f / s;
            out[(size_t)tg * 2 + 1] = e1 / s;
            float* idxf = out + (size_t)TOKENS * 2;
            idxf[(size_t)tg * 2 + 0] = (float)i1;
            idxf[(size_t)tg * 2 + 1] = (float)i2;
        }
    }
}

extern "C" void kernel_launch(void* const* d_in, const int* in_sizes, int n_in,
                              void* d_out, int out_size, void* d_ws, size_t ws_size,
                              hipStream_t stream) {
    const float* x = (const float*)d_in[0];
    const float* W = (const float*)d_in[1];
    const float* b = (const float*)d_in[2];
    float* out = (float*)d_out;
    float* wt = (float*)d_ws;   // 2048*64*4 = 512 KB scratch

    wtrans_kernel<<<DIM / 128, 256, 0, stream>>>(W, wt);
    router_kernel<<<TOKENS / BT, 256, 0, stream>>>(x, wt, b, out);
}

// Round 2
// 248.929 us; speedup vs baseline: 1.7919x; 1.7919x over previous
//
#include <hip/hip_runtime.h>
#include <math.h>

#define TOKENS 16384
#define DIM    2048
#define NE     64
#define BT     64                    // tokens per block
#define KC     32                    // k per chunk (per slice)
#define SLICE_K (DIM / 2)            // 1024 per slice group
#define NPHASE (SLICE_K / KC)        // 32 phases

// LDS layout (floats): 4 regions of 2048 per (buf,slice): x then w
#define OFFX(b,s) ((((b)*2 + (s))*2 + 0) * 2048)
#define OFFW(b,s) ((((b)*2 + (s))*2 + 1) * 2048)
#define RED_OFF  4096                // reuse buf0/slice1 area after main loop
#define LOGT_OFF 8192                // reuse buf1/slice0 area after main loop

// ---------------- Kernel A: transpose W [64][2048] -> wt [2048][64] ----------------
__global__ __launch_bounds__(256) void wtrans_kernel(const float* __restrict__ W,
                                                     float* __restrict__ wt) {
    __shared__ float tile[64 * 129];
    const int k0 = blockIdx.x * 128;
    const int tid = threadIdx.x;
    const int half = tid >> 7;
    const int c = tid & 127;
    for (int r = 0; r < 32; ++r) {
        int e = r * 2 + half;
        tile[e * 129 + c] = W[e * DIM + k0 + c];
    }
    __syncthreads();
    const int ec = tid & 63;
    const int kq = tid >> 6;
    for (int p = 0; p < 32; ++p) {
        int kr = p * 4 + kq;
        wt[(k0 + kr) * 64 + ec] = tile[ec * 129 + kr];
    }
}

__device__ __forceinline__ void async_f4(const float* g, float* l) {
    __builtin_amdgcn_global_load_lds((const __attribute__((address_space(1))) void*)g,
                                     (__attribute__((address_space(3))) void*)l,
                                     16, 0, 0);
}

// ---------------- Kernel B: fused logits GEMM + top-2 + softmax ----------------
// 512 threads = 2 slice-groups of 256; slice s owns k in [s*1024, s*1024+1024).
// Per-thread tile: 4 tokens x 4 experts. Double-buffered async LDS staging.
__global__ __launch_bounds__(512, 2) void router_kernel(const float* __restrict__ x,
                                                        const float* __restrict__ wt,
                                                        const float* __restrict__ b,
                                                        float* __restrict__ out) {
    __shared__ __align__(16) float lds[16384];   // 64 KB

    const int tid  = threadIdx.x;
    const int s    = tid >> 8;        // slice 0/1
    const int ts   = tid & 255;       // thread within slice
    const int wv   = ts >> 6;         // wave within slice (0..3)
    const int lane = tid & 63;
    const int t0   = blockIdx.x * BT;

    // ---- staging address precompute (2 x-instrs + 2 w-instrs per thread/phase) ----
    // x tile: 64 rows x 32 floats (8 float4/row), XOR-swizzled: slot(row,c) holds
    // global column (c ^ ((row>>2)&3)). w tile: [k][e] linear, 32 x 64 floats.
    const float* gx[2]; const float* gw[2];
    float* lx[2]; float* lw[2];
    #pragma unroll
    for (int p = 0; p < 2; ++p) {
        int slot = p * 256 + ts;
        int row  = slot >> 3;
        int col  = slot & 7;
        int csrc = col ^ ((row >> 2) & 3);
        gx[p] = x + (size_t)(t0 + row) * DIM + s * SLICE_K + csrc * 4;
        gw[p] = wt + (size_t)s * SLICE_K * NE + (size_t)slot * 4;
        lx[p] = &lds[OFFX(0, s) + (p * 256 + wv * 64) * 4];
        lw[p] = &lds[OFFW(0, s) + (p * 256 + wv * 64) * 4];
    }

    auto stage = [&](int kc, int buf) {
        const int bo = buf * 8192;
        #pragma unroll
        for (int p = 0; p < 2; ++p)
            async_f4(gx[p] + kc * KC, lx[p] + bo);
        #pragma unroll
        for (int p = 0; p < 2; ++p)
            async_f4(gw[p] + (size_t)kc * KC * NE, lw[p] + bo);
    };

    const int eg = ts & 15;           // expert group: experts eg*4 .. eg*4+3
    const int tg = ts >> 4;           // token group: tokens tg*4 .. tg*4+3
    const int sr = tg & 3;            // x read swizzle

    float acc[4][4] = {};

    stage(0, 0);
    __syncthreads();

    for (int kc = 0; kc < NPHASE; ++kc) {
        const int cur = kc & 1;
        if (kc + 1 < NPHASE) stage(kc + 1, cur ^ 1);   // async, lands during compute

        const float4* x4 = (const float4*)&lds[OFFX(0, s) + cur * 8192];
        const float4* w4 = (const float4*)&lds[OFFW(0, s) + cur * 8192];

        #pragma unroll 2
        for (int k4 = 0; k4 < KC / 4; ++k4) {
            const int xc = k4 ^ sr;
            float4 xa[4], wa[4];
            #pragma unroll
            for (int i = 0; i < 4; ++i) xa[i] = x4[(tg * 4 + i) * 8 + xc];
            #pragma unroll
            for (int j = 0; j < 4; ++j) wa[j] = w4[(k4 * 4 + j) * 16 + eg];
            #pragma unroll
            for (int i = 0; i < 4; ++i) {
                const float* xi = (const float*)&xa[i];
                #pragma unroll
                for (int kx = 0; kx < 4; ++kx) {
                    const float* wj = (const float*)&wa[kx];
                    acc[i][0] += xi[kx] * wj[0];
                    acc[i][1] += xi[kx] * wj[1];
                    acc[i][2] += xi[kx] * wj[2];
                    acc[i][3] += xi[kx] * wj[3];
                }
            }
        }
        __syncthreads();
    }

    // ---- cross-slice reduce: slice1 -> LDS, slice0 adds ----
    float4* red = (float4*)&lds[RED_OFF];
    if (s == 1) {
        #pragma unroll
        for (int i = 0; i < 4; ++i)
            red[i * 256 + ts] = make_float4(acc[i][0], acc[i][1], acc[i][2], acc[i][3]);
    }
    __syncthreads();

    if (s == 0) {
        const float4 bb = *(const float4*)&b[eg * 4];
        float* logits_out = out + (size_t)TOKENS * 4;
        #pragma unroll
        for (int i = 0; i < 4; ++i) {
            float4 r = red[i * 256 + ts];
            float4 v;
            v.x = acc[i][0] + r.x + bb.x;
            v.y = acc[i][1] + r.y + bb.y;
            v.z = acc[i][2] + r.z + bb.z;
            v.w = acc[i][3] + r.w + bb.w;
            *(float4*)&logits_out[(size_t)(t0 + tg * 4 + i) * NE + eg * 4] = v;
            *(float4*)&lds[LOGT_OFF + (tg * 4 + i) * NE + eg * 4] = v;
        }
    }
    __syncthreads();

    // ---- top-2 + softmax: 8 waves x 8 tokens ----
    const int wvg = tid >> 6;
    for (int r = 0; r < 8; ++r) {
        const int t = wvg * 8 + r;
        const float v = lds[LOGT_OFF + t * NE + lane];

        float v1 = v; int i1 = lane;
        #pragma unroll
        for (int off = 32; off >= 1; off >>= 1) {
            float ov = __shfl_xor(v1, off, 64);
            int   oi = __shfl_xor(i1, off, 64);
            if (ov > v1 || (ov == v1 && oi < i1)) { v1 = ov; i1 = oi; }
        }
        float vm = (lane == i1) ? -INFINITY : v;
        float v2 = vm; int i2 = lane;
        #pragma unroll
        for (int off = 32; off >= 1; off >>= 1) {
            float ov = __shfl_xor(v2, off, 64);
            int   oi = __shfl_xor(i2, off, 64);
            if (ov > v2 || (ov == v2 && oi < i2)) { v2 = ov; i2 = oi; }
        }

        if (lane == 0) {
            const int tg_ = t0 + t;
            float e1 = expf(v2 - v1);
            float sden = 1.0f + e1;
            out[(size_t)tg_ * 2 + 0] = 1.0f / sden;
            out[(size_t)tg_ * 2 + 1] = e1 / sden;
            float* idxf = out + (size_t)TOKENS * 2;
            idxf[(size_t)tg_ * 2 + 0] = (float)i1;
            idxf[(size_t)tg_ * 2 + 1] = (float)i2;
        }
    }
}

extern "C" void kernel_launch(void* const* d_in, const int* in_sizes, int n_in,
                              void* d_out, int out_size, void* d_ws, size_t ws_size,
                              hipStream_t stream) {
    const float* x = (const float*)d_in[0];
    const float* W = (const float*)d_in[1];
    const float* b = (const float*)d_in[2];
    float* out = (float*)d_out;
    float* wt = (float*)d_ws;   // 2048*64*4 = 512 KB scratch

    wtrans_kernel<<<DIM / 128, 256, 0, stream>>>(W, wt);
    router_kernel<<<TOKENS / BT, 512, 0, stream>>>(x, wt, b, out);
}

// Round 3
// 236.869 us; speedup vs baseline: 1.8831x; 1.0509x over previous
//
#include <hip/hip_runtime.h>
#include <math.h>

#define TOKENS 16384
#define DIM    2048
#define NE     64
#define BT     32                    // tokens per block
#define KC     32                    // k per phase (per slice)
#define SLICE_K (DIM / 2)            // 1024
#define NPHASE (SLICE_K / KC)        // 32

// ---------------- Kernel A: transpose W [64][2048] -> wt [2048][64] ----------------
// 256 blocks, no LDS: scatter-read (512 KB total, L2-friendly), coalesced write.
__global__ __launch_bounds__(256) void wtrans_kernel(const float* __restrict__ W,
                                                     float* __restrict__ wt) {
    const int k0 = blockIdx.x * 8;
    const int ts = threadIdx.x;
    const int e  = ts & 63;
    const int jr = ts >> 6;          // 0..3 -> k pair
    float2 v = *(const float2*)&W[(size_t)e * DIM + k0 + jr * 2];
    wt[(size_t)(k0 + jr * 2    ) * NE + e] = v.x;
    wt[(size_t)(k0 + jr * 2 + 1) * NE + e] = v.y;
}

__device__ __forceinline__ void async_f4(const float* g, float* l) {
    __builtin_amdgcn_global_load_lds((const __attribute__((address_space(1))) void*)g,
                                     (__attribute__((address_space(3))) void*)l,
                                     16, 0, 0);
}

// ---------------- Kernel B: fused logits GEMM + top-2 + softmax ----------------
// 512 threads = 2 K-slices x 256. Slice s owns k in [s*1024, s*1024+1024).
// Per-thread tile: 2 tokens x 4 experts. Double-buffered async LDS staging.
// Grid 512 -> 2 blocks/CU (16 waves/CU) so barrier bubbles overlap across blocks.
__global__ __launch_bounds__(512, 4) void router_kernel(const float* __restrict__ x,
                                                        const float* __restrict__ wt,
                                                        const float* __restrict__ b,
                                                        float* __restrict__ out) {
    __shared__ __align__(16) float lds[12288];   // 48 KB: 2 buf x 2 slice x (1024 x + 2048 w)

    const int tid  = threadIdx.x;
    const int s    = tid >> 8;        // slice 0/1 (wave-uniform)
    const int ts   = tid & 255;
    const int wv   = ts >> 6;         // wave within slice
    const int lane = tid & 63;
    const int t0   = blockIdx.x * BT;

    // ---- staging addresses ----
    // x tile: 32 rows x 32 floats, XOR-swizzled: phys col c holds global col c^(row&7).
    // w tile: [k][e] linear, 32 x 64 floats (2 f4/thread).
    const int xrow = ts >> 3, xcol = ts & 7;
    const float* gxp = x + (size_t)(t0 + xrow) * DIM + s * SLICE_K
                         + ((xcol ^ (xrow & 7)) * 4);
    const float* gwp = wt + (size_t)s * SLICE_K * NE + ts * 4;

    float* lx[2]; float* lw0[2]; float* lw1[2];
    #pragma unroll
    for (int bb = 0; bb < 2; ++bb) {
        float* base = &lds[s * 3072 + bb * 6144];
        lx[bb]  = base + (wv * 64) * 4;             // x slots [wv*64, wv*64+64)
        lw0[bb] = base + 1024 + (wv * 64) * 4;      // w slots [wv*64, ...)
        lw1[bb] = base + 1024 + (256 + wv * 64) * 4;
    }

    auto stage = [&](int kc, int bb) {
        const float* gw = gwp + (size_t)kc * KC * NE;
        async_f4(gxp + kc * KC, lx[bb]);
        async_f4(gw,            lw0[bb]);
        async_f4(gw + 1024,     lw1[bb]);
    };

    const int eg = ts & 15;           // experts eg*4 .. eg*4+3
    const int tg = ts >> 4;           // tokens tg*2, tg*2+1

    float acc[2][4] = {};

    stage(0, 0);
    __syncthreads();

    for (int kc = 0; kc < NPHASE; ++kc) {
        const int cur = kc & 1;
        if (kc + 1 < NPHASE) stage(kc + 1, cur ^ 1);   // lands during compute

        const float* base = &lds[s * 3072 + cur * 6144];
        const float4* x4 = (const float4*)base;
        const float4* w4 = (const float4*)(base + 1024);

        #pragma unroll 2
        for (int c = 0; c < 8; ++c) {
            float4 xa[2], wa[4];
            #pragma unroll
            for (int i = 0; i < 2; ++i) {
                const int r = tg * 2 + i;
                xa[i] = x4[r * 8 + (c ^ (r & 7))];
            }
            #pragma unroll
            for (int j = 0; j < 4; ++j) wa[j] = w4[(c * 4 + j) * 16 + eg];
            #pragma unroll
            for (int i = 0; i < 2; ++i) {
                const float* xi = (const float*)&xa[i];
                #pragma unroll
                for (int kx = 0; kx < 4; ++kx) {
                    const float* wj = (const float*)&wa[kx];
                    acc[i][0] += xi[kx] * wj[0];
                    acc[i][1] += xi[kx] * wj[1];
                    acc[i][2] += xi[kx] * wj[2];
                    acc[i][3] += xi[kx] * wj[3];
                }
            }
        }
        __syncthreads();
    }

    // ---- cross-slice reduce (buf0 region is dead: last phase read buf1) ----
    float4* red = (float4*)&lds[0];                   // 2048 floats
    if (s == 1) {
        #pragma unroll
        for (int i = 0; i < 2; ++i)
            red[i * 256 + ts] = make_float4(acc[i][0], acc[i][1], acc[i][2], acc[i][3]);
    }
    __syncthreads();

    float* logt = &lds[2048];                         // 2048 floats (32 x 64)
    if (s == 0) {
        const float4 bb4 = *(const float4*)&b[eg * 4];
        float* logits_out = out + (size_t)TOKENS * 4;
        #pragma unroll
        for (int i = 0; i < 2; ++i) {
            float4 r = red[i * 256 + ts];
            float4 v;
            v.x = acc[i][0] + r.x + bb4.x;
            v.y = acc[i][1] + r.y + bb4.y;
            v.z = acc[i][2] + r.z + bb4.z;
            v.w = acc[i][3] + r.w + bb4.w;
            const int t = tg * 2 + i;
            *(float4*)&logits_out[(size_t)(t0 + t) * NE + eg * 4] = v;
            *(float4*)&logt[t * NE + eg * 4] = v;
        }
    }
    __syncthreads();

    // ---- top-2 + softmax: 8 waves x 4 tokens ----
    const int wvg = tid >> 6;
    for (int r = 0; r < 4; ++r) {
        const int t = wvg * 4 + r;
        const float v = logt[t * NE + lane];

        float v1 = v; int i1 = lane;
        #pragma unroll
        for (int off = 32; off >= 1; off >>= 1) {
            float ov = __shfl_xor(v1, off, 64);
            int   oi = __shfl_xor(i1, off, 64);
            if (ov > v1 || (ov == v1 && oi < i1)) { v1 = ov; i1 = oi; }
        }
        float vm = (lane == i1) ? -INFINITY : v;
        float v2 = vm; int i2 = lane;
        #pragma unroll
        for (int off = 32; off >= 1; off >>= 1) {
            float ov = __shfl_xor(v2, off, 64);
            int   oi = __shfl_xor(i2, off, 64);
            if (ov > v2 || (ov == v2 && oi < i2)) { v2 = ov; i2 = oi; }
        }

        if (lane == 0) {
            const int tok = t0 + t;
            float e1 = expf(v2 - v1);
            float sden = 1.0f + e1;
            out[(size_t)tok * 2 + 0] = 1.0f / sden;
            out[(size_t)tok * 2 + 1] = e1 / sden;
            float* idxf = out + (size_t)TOKENS * 2;
            idxf[(size_t)tok * 2 + 0] = (float)i1;
            idxf[(size_t)tok * 2 + 1] = (float)i2;
        }
    }
}

extern "C" void kernel_launch(void* const* d_in, const int* in_sizes, int n_in,
                              void* d_out, int out_size, void* d_ws, size_t ws_size,
                              hipStream_t stream) {
    const float* x = (const float*)d_in[0];
    const float* W = (const float*)d_in[1];
    const float* b = (const float*)d_in[2];
    float* out = (float*)d_out;
    float* wt = (float*)d_ws;   // 2048*64*4 = 512 KB scratch

    wtrans_kernel<<<DIM / 8, 256, 0, stream>>>(W, wt);
    router_kernel<<<TOKENS / BT, 512, 0, stream>>>(x, wt, b, out);
}